// Round 4
// baseline (1606.914 us; speedup 1.0000x reference)
//
#include <hip/hip_runtime.h>
#include <math.h>

#define BATCH   16384
#define DIMS    64
#define WID     128
#define KN      8
#define NP      23        // 3*KN - 1
#define NCOL    (DIMS * NP)   // 1472 param columns
#define NLAYERS 8
#define BI_F    4.0f
#define C1SP    0.5399061f    // softplus(C1SP) + 0.001 ~= 1.0  (boundary knot)

#define PF_WOUT (NLAYERS * NCOL * WID)        // per-flow Wout elems
#define PF_W1   (NLAYERS * WID * DIMS)        // per-flow W1 elems

// compiler memory fence: forbids reordering LDS writes/reads across phase
// boundaries (no data-dep exists there; TBAA would otherwise allow hoisting).
// HW DS pipe is in-order per wave, so compile-order == execution-order.
#define MEMFENCE() asm volatile("" ::: "memory")

typedef short s16x8 __attribute__((ext_vector_type(8)));
typedef float f32x4 __attribute__((ext_vector_type(4)));

__device__ __forceinline__ unsigned short f2bf(float f) {
    unsigned int u = __builtin_bit_cast(unsigned int, f);
    unsigned int r = (u + 0x7FFFu + ((u >> 16) & 1u)) >> 16;
    return (unsigned short)r;
}
__device__ __forceinline__ float bf2f(unsigned short u) {
    return __builtin_bit_cast(float, (unsigned int)u << 16);
}
__device__ __forceinline__ uint2 pack4(f32x4 a) {
    uint2 u;
    u.x = (unsigned)f2bf(a[0]) | ((unsigned)f2bf(a[1]) << 16);
    u.y = (unsigned)f2bf(a[2]) | ((unsigned)f2bf(a[3]) << 16);
    return u;
}

// ---------------------------------------------------------------------------
// Pre-mask MADE weights -> bf16 workspace; zero the ld accumulators.
// ---------------------------------------------------------------------------
__global__ __launch_bounds__(256) void premask_kernel(
    const float* __restrict__ f_wout, const float* __restrict__ g_wout,
    const float* __restrict__ f_w1,   const float* __restrict__ g_w1,
    unsigned short* __restrict__ womask, unsigned short* __restrict__ w1mask,
    float* __restrict__ ldf, float* __restrict__ ldg)
{
    const int idx    = blockIdx.x * 256 + threadIdx.x;
    const int stride = gridDim.x * 256;

    const int totw = 2 * PF_WOUT;
    for (int i = idx; i < totw; i += stride) {
        int fl = i / PF_WOUT;
        int r  = i % PF_WOUT;
        int h  = r % WID;
        int o  = (r / WID) % NCOL;
        int d  = o / NP;
        int hd = h % (DIMS - 1) + 1;            // hid_deg
        const float* src = fl ? g_wout : f_wout;
        womask[i] = (hd <= d) ? f2bf(src[r]) : (unsigned short)0;
    }

    const int tot1 = 2 * PF_W1;
    for (int i = idx; i < tot1; i += stride) {
        int fl = i / PF_W1;
        int r  = i % PF_W1;
        int c  = r % DIMS;
        int w  = (r / DIMS) % WID;
        int deg = w % (DIMS - 1) + 1;           // hid_deg
        const float* src = fl ? g_w1 : f_w1;
        w1mask[i] = (c < deg) ? f2bf(src[r]) : (unsigned short)0;
    }

    for (int i = idx; i < 2 * BATCH; i += stride) {
        if (i < BATCH) ldf[i] = 0.0f;
        else           ldg[i - BATCH] = 0.0f;
    }
}

// ---------------------------------------------------------------------------
// RQS spline for one (batch-row, dim). p0 points at the 23 bf16 params
// (stride 16 elements) in the wave's LDS transpose buffer.
// ---------------------------------------------------------------------------
__device__ __forceinline__ float2 rqs_spline(const unsigned short* p0, float xraw)
{
    float pw[KN], ph[KN], pd[KN - 1];
    #pragma unroll
    for (int j = 0; j < KN; ++j)     pw[j] = bf2f(p0[j * 16]);
    #pragma unroll
    for (int j = 0; j < KN; ++j)     ph[j] = bf2f(p0[(KN + j) * 16]);
    #pragma unroll
    for (int j = 0; j < KN - 1; ++j) pd[j] = bf2f(p0[(2 * KN + j) * 16]);

    // softmax without max-subtract (logits bounded ~O(1) for this model)
    float sw = 0.0f, sh = 0.0f;
    #pragma unroll
    for (int j = 0; j < KN; ++j) {
        pw[j] = __expf(pw[j]); sw += pw[j];
        ph[j] = __expf(ph[j]); sh += ph[j];
    }
    const float cmul = 8.0f / 1.01f;            // 2*Bi/(1+ADJ)
    const float cadd = cmul * 0.00125f;         // 2*Bi*ADJ/(K*(1+ADJ))
    const float rw = cmul * __builtin_amdgcn_rcpf(sw);
    const float rh = cmul * __builtin_amdgcn_rcpf(sh);

    const bool inside = (xraw > -BI_F) && (xraw < BI_F);
    const float xcl = fminf(fmaxf(xraw, -BI_F), BI_F);

    // bin select: running cumsum + branchless select; bin 0 pre-selected.
    float xk = -BI_F, yk = -BI_F;
    float xk1 = -BI_F + fmaf(pw[0], rw, cadd);
    float yk1 = -BI_F + fmaf(ph[0], rh, cadd);
    float dlk = C1SP, dlk1 = pd[0];
    float cx = xk1, cy = yk1;
    #pragma unroll
    for (int i = 1; i < KN; ++i) {
        const float nx = cx + fmaf(pw[i], rw, cadd);
        const float ny = cy + fmaf(ph[i], rh, cadd);
        const bool cc = (xcl >= cx);
        xk   = cc ? cx : xk;    yk   = cc ? cy : yk;
        xk1  = cc ? nx : xk1;   yk1  = cc ? ny : yk1;
        dlk  = cc ? pd[i - 1] : dlk;
        dlk1 = cc ? ((i == KN - 1) ? C1SP : pd[i]) : dlk1;
        cx = nx; cy = ny;
    }
    // only the two selected derivative knots get a softplus
    const float dk  = __logf(1.0f + __expf(dlk))  + 0.001f;
    const float dk1 = __logf(1.0f + __expf(dlk1)) + 0.001f;

    const float invw = __builtin_amdgcn_rcpf(xk1 - xk);
    const float sk   = (yk1 - yk) * invw;
    const float xi   = (xcl - xk) * invw;
    const float omx  = 1.0f - xi;
    const float xo2  = xi * omx;
    const float den  = fmaf(dk1 + dk - 2.0f * sk, xo2, sk);
    const float rden = __builtin_amdgcn_rcpf(den);
    const float outv = fmaf((yk1 - yk) * rden, fmaf(sk * xi, xi, dk * xo2), yk);
    const float numl = fmaf(dk1 * xi, xi, fmaf(2.0f * sk, xo2, dk * omx * omx));
    const float ldj  = __logf(sk * sk * numl * (rden * rden));
    return make_float2(inside ? outv : xraw, inside ? ldj : 0.0f);
}

// ---------------------------------------------------------------------------
// One MAF layer. Block = 4 waves x 64 batch rows, all waves on the SAME
// 32-dim half (L1 reuse of the B-stream). Wave = 16 rows x 2 chunks.
// Barrier-free across waves: all dataflow wave-private; ld via atomicAdd.
// blockIdx.y: bit0 = dim-half, bit1 = flow.
// ---------------------------------------------------------------------------
__global__ __launch_bounds__(256, 4) void layer_kernel(
    const float* __restrict__ xin_f, const float* __restrict__ xin_g,
    float* __restrict__ xout_f,      float* __restrict__ xout_g,
    const unsigned short* __restrict__ w1m_f, const unsigned short* __restrict__ w1m_g,
    const float* __restrict__ b1_f,  const float* __restrict__ b1_g,
    const unsigned short* __restrict__ wom_f, const unsigned short* __restrict__ wom_g,
    const float* __restrict__ bo_f,  const float* __restrict__ bo_g,
    float* __restrict__ ld_f,        float* __restrict__ ld_g)
{
    // per-wave 9216B buffer, time-shared: Hs (16x136, 4352B) then P-transpose
    // (288 cols x 16 rows bf16 = 9216B, two phases). MEMFENCE() at every
    // phase boundary keeps compile-order == DS-pipe order.
    __shared__ __align__(16) unsigned short buf[4][4608];

    const int t    = threadIdx.x;
    const int wv   = t >> 6;
    const int ln   = t & 63;
    const int m    = ln & 15;
    const int q    = ln >> 4;
    const int flow = blockIdx.y >> 1;
    const int dh   = blockIdx.y & 1;             // dim half: chunks 2*dh, 2*dh+1
    const int r0   = blockIdx.x * 64 + wv * 16;  // this wave's first batch row

    const float* xin          = flow ? xin_g : xin_f;
    float*       xout         = flow ? xout_g : xout_f;
    const unsigned short* w1m = flow ? w1m_g : w1m_f;
    const float* b1           = flow ? b1_g  : b1_f;
    const unsigned short* wom = flow ? wom_g : wom_f;
    const float* bo           = flow ? bo_g  : bo_f;
    float*       ldp          = flow ? ld_g  : ld_f;

    unsigned short* bw = &buf[wv][0];

    // ---- GEMM1: A-frags from x (global fp32 -> bf16) ----
    const float* xrow = xin + (size_t)(r0 + m) * DIMS;
    s16x8 xa[2];
    #pragma unroll
    for (int ks = 0; ks < 2; ++ks) {
        float4 v0 = *(const float4*)(xrow + ks * 32 + q * 8);
        float4 v1 = *(const float4*)(xrow + ks * 32 + q * 8 + 4);
        s16x8 a;
        a[0] = (short)f2bf(v0.x); a[1] = (short)f2bf(v0.y);
        a[2] = (short)f2bf(v0.z); a[3] = (short)f2bf(v0.w);
        a[4] = (short)f2bf(v1.x); a[5] = (short)f2bf(v1.y);
        a[6] = (short)f2bf(v1.z); a[7] = (short)f2bf(v1.w);
        xa[ks] = a;
    }
    {
        f32x4 hacc[8];
        #pragma unroll
        for (int nt = 0; nt < 8; ++nt) {
            float bv = b1[nt * 16 + m];
            hacc[nt] = (f32x4){bv, bv, bv, bv};
        }
        #pragma unroll
        for (int ks = 0; ks < 2; ++ks) {
            #pragma unroll
            for (int nt = 0; nt < 8; ++nt) {
                s16x8 bfr = *(const s16x8*)(w1m + (nt * 16 + m) * DIMS + ks * 32 + q * 8);
                hacc[nt] = __builtin_amdgcn_mfma_f32_16x16x32_bf16(xa[ks], bfr, hacc[nt], 0, 0, 0);
            }
        }
        // ReLU -> bf16 -> Hs (row-major, pitch 136)
        #pragma unroll
        for (int nt = 0; nt < 8; ++nt) {
            #pragma unroll
            for (int rr = 0; rr < 4; ++rr) {
                bw[(q * 4 + rr) * 136 + nt * 16 + m] = f2bf(fmaxf(hacc[nt][rr], 0.0f));
            }
        }
    }
    MEMFENCE();

    // ---- GEMM2 A-frags from Hs (b128, wave-private) ----
    s16x8 af[4];
    #pragma unroll
    for (int ks = 0; ks < 4; ++ks)
        af[ks] = *(const s16x8*)(bw + m * 136 + ks * 32 + q * 8);
    MEMFENCE();

    float ldsum = 0.0f;

    #pragma unroll 1
    for (int cc = 0; cc < 2; ++cc) {
        const int c = dh * 2 + cc;               // global chunk (16 dims)
        const unsigned short* wchunk = wom + (size_t)c * 368 * WID;
        const float* bchunk = bo + c * 368;

        f32x4 acc[23];
        #pragma unroll
        for (int nt = 0; nt < 23; ++nt) {
            float bv = bchunk[nt * 16 + m];
            acc[nt] = (f32x4){bv, bv, bv, bv};
        }
        #pragma unroll
        for (int ks = 0; ks < 4; ++ks) {
            #pragma unroll
            for (int nt = 0; nt < 23; ++nt) {
                const s16x8 bfr = *(const s16x8*)(wchunk +
                    (size_t)(nt * 16 + m) * WID + ks * 32 + q * 8);
                acc[nt] = __builtin_amdgcn_mfma_f32_16x16x32_bf16(af[ks], bfr, acc[nt], 0, 0, 0);
            }
        }

        // ---- phase A: transpose tiles 0..17 (cols 0..287), spline dl 0..11 ----
        #pragma unroll
        for (int nt = 0; nt < 18; ++nt)
            *(uint2*)(bw + (nt * 16 + m) * 16 + q * 4) = pack4(acc[nt]);
        MEMFENCE();

        #pragma unroll
        for (int sub = 0; sub < 3; ++sub) {
            const int dl = sub * 4 + q;
            const int d  = c * 16 + dl;
            const unsigned short* p0 = bw + (dl * NP) * 16 + m;
            const float xraw = xin[(size_t)(r0 + m) * DIMS + d];
            float2 r = rqs_spline(p0, xraw);
            xout[(size_t)(r0 + m) * DIMS + (DIMS - 1 - d)] = r.x;
            ldsum += r.y;
        }
        MEMFENCE();

        // ---- phase B: tiles 17..22 re-homed at col-272, spline dl 12..15 ----
        #pragma unroll
        for (int nt = 17; nt < 23; ++nt)
            *(uint2*)(bw + ((nt * 16 + m) - 272) * 16 + q * 4) = pack4(acc[nt]);
        MEMFENCE();

        {
            const int dl = 12 + q;
            const int d  = c * 16 + dl;
            const unsigned short* p0 = bw + (dl * NP - 272) * 16 + m;
            const float xraw = xin[(size_t)(r0 + m) * DIMS + d];
            float2 r = rqs_spline(p0, xraw);
            xout[(size_t)(r0 + m) * DIMS + (DIMS - 1 - d)] = r.x;
            ldsum += r.y;
        }
        MEMFENCE();
    }

    // ---- ld: reduce over the 4 q-lanes per row, then global atomic ----
    float v = ldsum + __shfl_xor(ldsum, 16, 64);
    v = v + __shfl_xor(v, 32, 64);
    if (ln < 16) atomicAdd(&ldp[r0 + ln], v);
}

// ---------------------------------------------------------------------------
extern "C" void kernel_launch(void* const* d_in, const int* in_sizes, int n_in,
                              void* d_out, int out_size, void* d_ws, size_t ws_size,
                              hipStream_t stream)
{
    const float* x      = (const float*)d_in[0];
    const float* y      = (const float*)d_in[1];
    const float* f_W1   = (const float*)d_in[2];
    const float* f_b1   = (const float*)d_in[3];
    const float* f_Wout = (const float*)d_in[4];
    const float* f_bout = (const float*)d_in[5];
    const float* g_W1   = (const float*)d_in[6];
    const float* g_b1   = (const float*)d_in[7];
    const float* g_Wout = (const float*)d_in[8];
    const float* g_bout = (const float*)d_in[9];

    float* out = (float*)d_out;
    float* xo  = out;                               // [B, D]
    float* ldf = out + (size_t)BATCH * DIMS;        // [B]
    float* yo  = ldf + BATCH;                       // [B, D]
    float* ldg = yo + (size_t)BATCH * DIMS;         // [B]

    unsigned short* womask = (unsigned short*)d_ws;           // 2*PF_WOUT bf16
    unsigned short* w1mask = womask + 2 * (size_t)PF_WOUT;    // 2*PF_W1 bf16
    float* xA_f = (float*)(w1mask + 2 * (size_t)PF_W1);       // [B,D] ping (f)
    float* xA_g = xA_f + (size_t)BATCH * DIMS;                // [B,D] ping (g)

    premask_kernel<<<dim3(2048), dim3(256), 0, stream>>>(
        f_Wout, g_Wout, f_W1, g_W1, womask, w1mask, ldf, ldg);

    for (int l = 0; l < NLAYERS; ++l) {
        const float* inf = (l == 0) ? x : ((l & 1) ? xA_f : xo);
        const float* ing = (l == 0) ? y : ((l & 1) ? xA_g : yo);
        float* outf = (l & 1) ? xo : xA_f;
        float* outg = (l & 1) ? yo : xA_g;

        layer_kernel<<<dim3(BATCH / 64, 4), dim3(256), 0, stream>>>(
            inf, ing, outf, outg,
            w1mask + (size_t)l * WID * DIMS,
            w1mask + (size_t)PF_W1 + (size_t)l * WID * DIMS,
            f_b1 + (size_t)l * WID, g_b1 + (size_t)l * WID,
            womask + (size_t)l * NCOL * WID,
            womask + (size_t)PF_WOUT + (size_t)l * NCOL * WID,
            f_bout + (size_t)l * NCOL, g_bout + (size_t)l * NCOL,
            ldf, ldg);
    }
}

// Round 5
// 903.398 us; speedup vs baseline: 1.7787x; 1.7787x over previous
//
#include <hip/hip_runtime.h>
#include <math.h>

#define BATCH   16384
#define DIMS    64
#define WID     128
#define KN      8
#define NP      23        // 3*KN - 1
#define NCOL    (DIMS * NP)   // 1472 param columns
#define NLAYERS 8
#define BI_F    4.0f
#define C1SP    0.5399061f    // softplus(C1SP) + 0.001 ~= 1.0  (boundary knot)

#define PF_WOUT (NLAYERS * NCOL * WID)        // per-flow Wout elems
#define PF_W1   (NLAYERS * WID * DIMS)        // per-flow W1 elems

// compiler memory fence: forbids reordering LDS writes/reads across phase
// boundaries (no data-dep exists there; TBAA would otherwise allow hoisting).
// HW DS pipe is in-order per wave, so compile-order == execution-order.
#define MEMFENCE() asm volatile("" ::: "memory")

typedef short s16x8 __attribute__((ext_vector_type(8)));
typedef float f32x4 __attribute__((ext_vector_type(4)));

__device__ __forceinline__ unsigned short f2bf(float f) {
    unsigned int u = __builtin_bit_cast(unsigned int, f);
    unsigned int r = (u + 0x7FFFu + ((u >> 16) & 1u)) >> 16;
    return (unsigned short)r;
}
__device__ __forceinline__ float bf2f(unsigned short u) {
    return __builtin_bit_cast(float, (unsigned int)u << 16);
}
__device__ __forceinline__ uint2 pack4(f32x4 a) {
    uint2 u;
    u.x = (unsigned)f2bf(a[0]) | ((unsigned)f2bf(a[1]) << 16);
    u.y = (unsigned)f2bf(a[2]) | ((unsigned)f2bf(a[3]) << 16);
    return u;
}

// ---------------------------------------------------------------------------
// Pre-mask MADE weights -> bf16 workspace; zero the ld accumulators.
// ---------------------------------------------------------------------------
__global__ __launch_bounds__(256) void premask_kernel(
    const float* __restrict__ f_wout, const float* __restrict__ g_wout,
    const float* __restrict__ f_w1,   const float* __restrict__ g_w1,
    unsigned short* __restrict__ womask, unsigned short* __restrict__ w1mask,
    float* __restrict__ ldf, float* __restrict__ ldg)
{
    const int idx    = blockIdx.x * 256 + threadIdx.x;
    const int stride = gridDim.x * 256;

    const int totw = 2 * PF_WOUT;
    for (int i = idx; i < totw; i += stride) {
        int fl = i / PF_WOUT;
        int r  = i % PF_WOUT;
        int h  = r % WID;
        int o  = (r / WID) % NCOL;
        int d  = o / NP;
        int hd = h % (DIMS - 1) + 1;            // hid_deg
        const float* src = fl ? g_wout : f_wout;
        womask[i] = (hd <= d) ? f2bf(src[r]) : (unsigned short)0;
    }

    const int tot1 = 2 * PF_W1;
    for (int i = idx; i < tot1; i += stride) {
        int fl = i / PF_W1;
        int r  = i % PF_W1;
        int c  = r % DIMS;
        int w  = (r / DIMS) % WID;
        int deg = w % (DIMS - 1) + 1;           // hid_deg
        const float* src = fl ? g_w1 : f_w1;
        w1mask[i] = (c < deg) ? f2bf(src[r]) : (unsigned short)0;
    }

    for (int i = idx; i < 2 * BATCH; i += stride) {
        if (i < BATCH) ldf[i] = 0.0f;
        else           ldg[i - BATCH] = 0.0f;
    }
}

// ---------------------------------------------------------------------------
// RQS spline for one (batch-row, dim). p0 points at the 23 bf16 params
// (stride 16 elements) in the wave's LDS transpose buffer.
// ---------------------------------------------------------------------------
__device__ __forceinline__ float2 rqs_spline(const unsigned short* p0, float xraw)
{
    float pw[KN], ph[KN], pd[KN - 1];
    #pragma unroll
    for (int j = 0; j < KN; ++j)     pw[j] = bf2f(p0[j * 16]);
    #pragma unroll
    for (int j = 0; j < KN; ++j)     ph[j] = bf2f(p0[(KN + j) * 16]);
    #pragma unroll
    for (int j = 0; j < KN - 1; ++j) pd[j] = bf2f(p0[(2 * KN + j) * 16]);

    // softmax without max-subtract (logits bounded ~O(1) for this model)
    float sw = 0.0f, sh = 0.0f;
    #pragma unroll
    for (int j = 0; j < KN; ++j) {
        pw[j] = __expf(pw[j]); sw += pw[j];
        ph[j] = __expf(ph[j]); sh += ph[j];
    }
    const float cmul = 8.0f / 1.01f;            // 2*Bi/(1+ADJ)
    const float cadd = cmul * 0.00125f;         // 2*Bi*ADJ/(K*(1+ADJ))
    const float rw = cmul * __builtin_amdgcn_rcpf(sw);
    const float rh = cmul * __builtin_amdgcn_rcpf(sh);

    const bool inside = (xraw > -BI_F) && (xraw < BI_F);
    const float xcl = fminf(fmaxf(xraw, -BI_F), BI_F);

    // bin select: running cumsum + branchless select; bin 0 pre-selected.
    float xk = -BI_F, yk = -BI_F;
    float xk1 = -BI_F + fmaf(pw[0], rw, cadd);
    float yk1 = -BI_F + fmaf(ph[0], rh, cadd);
    float dlk = C1SP, dlk1 = pd[0];
    float cx = xk1, cy = yk1;
    #pragma unroll
    for (int i = 1; i < KN; ++i) {
        const float nx = cx + fmaf(pw[i], rw, cadd);
        const float ny = cy + fmaf(ph[i], rh, cadd);
        const bool cc = (xcl >= cx);
        xk   = cc ? cx : xk;    yk   = cc ? cy : yk;
        xk1  = cc ? nx : xk1;   yk1  = cc ? ny : yk1;
        dlk  = cc ? pd[i - 1] : dlk;
        dlk1 = cc ? ((i == KN - 1) ? C1SP : pd[i]) : dlk1;
        cx = nx; cy = ny;
    }
    // only the two selected derivative knots get a softplus
    const float dk  = __logf(1.0f + __expf(dlk))  + 0.001f;
    const float dk1 = __logf(1.0f + __expf(dlk1)) + 0.001f;

    const float invw = __builtin_amdgcn_rcpf(xk1 - xk);
    const float sk   = (yk1 - yk) * invw;
    const float xi   = (xcl - xk) * invw;
    const float omx  = 1.0f - xi;
    const float xo2  = xi * omx;
    const float den  = fmaf(dk1 + dk - 2.0f * sk, xo2, sk);
    const float rden = __builtin_amdgcn_rcpf(den);
    const float outv = fmaf((yk1 - yk) * rden, fmaf(sk * xi, xi, dk * xo2), yk);
    const float numl = fmaf(dk1 * xi, xi, fmaf(2.0f * sk, xo2, dk * omx * omx));
    const float ldj  = __logf(sk * sk * numl * (rden * rden));
    return make_float2(inside ? outv : xraw, inside ? ldj : 0.0f);
}

// ---------------------------------------------------------------------------
// One MAF layer. Block = 4 waves x 64 batch rows, all waves on the SAME
// 32-dim half (L1 reuse of the B-stream). Wave = 16 rows x 2 chunks.
// Barrier-free across waves: all dataflow wave-private; ld via atomicAdd.
// GEMM2 is N-outer in small tile groups: accumulators are written to LDS
// as soon as their K-loop finishes, keeping live VGPRs ~100 (NO SPILLS —
// R4's (256,4) bound made the allocator pick 64 VGPRs and spill acc[23],
// costing 800 MB/dispatch of scratch traffic).
// blockIdx.y: bit0 = dim-half, bit1 = flow.
// ---------------------------------------------------------------------------
__global__ __launch_bounds__(256, 2) void layer_kernel(
    const float* __restrict__ xin_f, const float* __restrict__ xin_g,
    float* __restrict__ xout_f,      float* __restrict__ xout_g,
    const unsigned short* __restrict__ w1m_f, const unsigned short* __restrict__ w1m_g,
    const float* __restrict__ b1_f,  const float* __restrict__ b1_g,
    const unsigned short* __restrict__ wom_f, const unsigned short* __restrict__ wom_g,
    const float* __restrict__ bo_f,  const float* __restrict__ bo_g,
    float* __restrict__ ld_f,        float* __restrict__ ld_g)
{
    // per-wave 9216B buffer, time-shared: Hs (16x136, 4352B) then P-transpose
    // (288 cols x 16 rows bf16, two phases). MEMFENCE() at every phase
    // boundary keeps compile-order == DS-pipe order.
    __shared__ __align__(16) unsigned short buf[4][4608];

    const int t    = threadIdx.x;
    const int wv   = t >> 6;
    const int ln   = t & 63;
    const int m    = ln & 15;
    const int q    = ln >> 4;
    const int flow = blockIdx.y >> 1;
    const int dh   = blockIdx.y & 1;             // dim half: chunks 2*dh, 2*dh+1
    const int r0   = blockIdx.x * 64 + wv * 16;  // this wave's first batch row

    const float* xin          = flow ? xin_g : xin_f;
    float*       xout         = flow ? xout_g : xout_f;
    const unsigned short* w1m = flow ? w1m_g : w1m_f;
    const float* b1           = flow ? b1_g  : b1_f;
    const unsigned short* wom = flow ? wom_g : wom_f;
    const float* bo           = flow ? bo_g  : bo_f;
    float*       ldp          = flow ? ld_g  : ld_f;

    unsigned short* bw = &buf[wv][0];

    // ---- GEMM1: A-frags from x (global fp32 -> bf16) ----
    const float* xrow = xin + (size_t)(r0 + m) * DIMS;
    s16x8 xa[2];
    #pragma unroll
    for (int ks = 0; ks < 2; ++ks) {
        float4 v0 = *(const float4*)(xrow + ks * 32 + q * 8);
        float4 v1 = *(const float4*)(xrow + ks * 32 + q * 8 + 4);
        s16x8 a;
        a[0] = (short)f2bf(v0.x); a[1] = (short)f2bf(v0.y);
        a[2] = (short)f2bf(v0.z); a[3] = (short)f2bf(v0.w);
        a[4] = (short)f2bf(v1.x); a[5] = (short)f2bf(v1.y);
        a[6] = (short)f2bf(v1.z); a[7] = (short)f2bf(v1.w);
        xa[ks] = a;
    }
    {
        f32x4 hacc[8];
        #pragma unroll
        for (int nt = 0; nt < 8; ++nt) {
            float bv = b1[nt * 16 + m];
            hacc[nt] = (f32x4){bv, bv, bv, bv};
        }
        #pragma unroll
        for (int ks = 0; ks < 2; ++ks) {
            #pragma unroll
            for (int nt = 0; nt < 8; ++nt) {
                s16x8 bfr = *(const s16x8*)(w1m + (nt * 16 + m) * DIMS + ks * 32 + q * 8);
                hacc[nt] = __builtin_amdgcn_mfma_f32_16x16x32_bf16(xa[ks], bfr, hacc[nt], 0, 0, 0);
            }
        }
        // ReLU -> bf16 -> Hs (row-major, pitch 136)
        #pragma unroll
        for (int nt = 0; nt < 8; ++nt) {
            #pragma unroll
            for (int rr = 0; rr < 4; ++rr) {
                bw[(q * 4 + rr) * 136 + nt * 16 + m] = f2bf(fmaxf(hacc[nt][rr], 0.0f));
            }
        }
    }
    MEMFENCE();

    // ---- GEMM2 A-frags from Hs (b128, wave-private) ----
    s16x8 af[4];
    #pragma unroll
    for (int ks = 0; ks < 4; ++ks)
        af[ks] = *(const s16x8*)(bw + m * 136 + ks * 32 + q * 8);
    MEMFENCE();

    float ldsum = 0.0f;

    #pragma unroll 1
    for (int cc = 0; cc < 2; ++cc) {
        const int c = dh * 2 + cc;               // global chunk (16 dims)
        const unsigned short* wchunk = wom + (size_t)c * 368 * WID;
        const float* bchunk = bo + c * 368;

        // ---- tiles 0..15 in groups of 4: compute, write to LDS, release ----
        #pragma unroll 1
        for (int g = 0; g < 4; ++g) {
            f32x4 a4[4];
            #pragma unroll
            for (int i = 0; i < 4; ++i) {
                float bv = bchunk[(g * 4 + i) * 16 + m];
                a4[i] = (f32x4){bv, bv, bv, bv};
            }
            #pragma unroll
            for (int ks = 0; ks < 4; ++ks) {
                #pragma unroll
                for (int i = 0; i < 4; ++i) {
                    const s16x8 bfr = *(const s16x8*)(wchunk +
                        (size_t)((g * 4 + i) * 16 + m) * WID + ks * 32 + q * 8);
                    a4[i] = __builtin_amdgcn_mfma_f32_16x16x32_bf16(af[ks], bfr, a4[i], 0, 0, 0);
                }
            }
            #pragma unroll
            for (int i = 0; i < 4; ++i)
                *(uint2*)(bw + ((g * 4 + i) * 16 + m) * 16 + q * 4) = pack4(a4[i]);
        }

        // ---- tiles 16..22: held in regs across phase-A splines ----
        f32x4 ah[7];
        #pragma unroll
        for (int i = 0; i < 7; ++i) {
            float bv = bchunk[(16 + i) * 16 + m];
            ah[i] = (f32x4){bv, bv, bv, bv};
        }
        #pragma unroll
        for (int ks = 0; ks < 4; ++ks) {
            #pragma unroll
            for (int i = 0; i < 7; ++i) {
                const s16x8 bfr = *(const s16x8*)(wchunk +
                    (size_t)((16 + i) * 16 + m) * WID + ks * 32 + q * 8);
                ah[i] = __builtin_amdgcn_mfma_f32_16x16x32_bf16(af[ks], bfr, ah[i], 0, 0, 0);
            }
        }
        // tiles 16,17 also belong to the phase-A region (cols 256..287)
        #pragma unroll
        for (int i = 0; i < 2; ++i)
            *(uint2*)(bw + ((16 + i) * 16 + m) * 16 + q * 4) = pack4(ah[i]);
        MEMFENCE();

        // ---- phase A splines: dl 0..11 (cols 0..275 all resident) ----
        #pragma unroll
        for (int sub = 0; sub < 3; ++sub) {
            const int dl = sub * 4 + q;
            const int d  = c * 16 + dl;
            const unsigned short* p0 = bw + (dl * NP) * 16 + m;
            const float xraw = xin[(size_t)(r0 + m) * DIMS + d];
            float2 r = rqs_spline(p0, xraw);
            xout[(size_t)(r0 + m) * DIMS + (DIMS - 1 - d)] = r.x;
            ldsum += r.y;
        }
        MEMFENCE();

        // ---- phase B: tiles 17..22 re-homed at col-272, splines dl 12..15 ----
        #pragma unroll
        for (int i = 1; i < 7; ++i)
            *(uint2*)(bw + (((16 + i) - 17) * 16 + m) * 16 + q * 4) = pack4(ah[i]);
        MEMFENCE();

        {
            const int dl = 12 + q;
            const int d  = c * 16 + dl;
            const unsigned short* p0 = bw + (dl * NP - 272) * 16 + m;
            const float xraw = xin[(size_t)(r0 + m) * DIMS + d];
            float2 r = rqs_spline(p0, xraw);
            xout[(size_t)(r0 + m) * DIMS + (DIMS - 1 - d)] = r.x;
            ldsum += r.y;
        }
        MEMFENCE();
    }

    // ---- ld: reduce over the 4 q-lanes per row, then global atomic ----
    float v = ldsum + __shfl_xor(ldsum, 16, 64);
    v = v + __shfl_xor(v, 32, 64);
    if (ln < 16) atomicAdd(&ldp[r0 + ln], v);
}

// ---------------------------------------------------------------------------
extern "C" void kernel_launch(void* const* d_in, const int* in_sizes, int n_in,
                              void* d_out, int out_size, void* d_ws, size_t ws_size,
                              hipStream_t stream)
{
    const float* x      = (const float*)d_in[0];
    const float* y      = (const float*)d_in[1];
    const float* f_W1   = (const float*)d_in[2];
    const float* f_b1   = (const float*)d_in[3];
    const float* f_Wout = (const float*)d_in[4];
    const float* f_bout = (const float*)d_in[5];
    const float* g_W1   = (const float*)d_in[6];
    const float* g_b1   = (const float*)d_in[7];
    const float* g_Wout = (const float*)d_in[8];
    const float* g_bout = (const float*)d_in[9];

    float* out = (float*)d_out;
    float* xo  = out;                               // [B, D]
    float* ldf = out + (size_t)BATCH * DIMS;        // [B]
    float* yo  = ldf + BATCH;                       // [B, D]
    float* ldg = yo + (size_t)BATCH * DIMS;         // [B]

    unsigned short* womask = (unsigned short*)d_ws;           // 2*PF_WOUT bf16
    unsigned short* w1mask = womask + 2 * (size_t)PF_WOUT;    // 2*PF_W1 bf16
    float* xA_f = (float*)(w1mask + 2 * (size_t)PF_W1);       // [B,D] ping (f)
    float* xA_g = xA_f + (size_t)BATCH * DIMS;                // [B,D] ping (g)

    premask_kernel<<<dim3(2048), dim3(256), 0, stream>>>(
        f_Wout, g_Wout, f_W1, g_W1, womask, w1mask, ldf, ldg);

    for (int l = 0; l < NLAYERS; ++l) {
        const float* inf = (l == 0) ? x : ((l & 1) ? xA_f : xo);
        const float* ing = (l == 0) ? y : ((l & 1) ? xA_g : yo);
        float* outf = (l & 1) ? xo : xA_f;
        float* outg = (l & 1) ? yo : xA_g;

        layer_kernel<<<dim3(BATCH / 64, 4), dim3(256), 0, stream>>>(
            inf, ing, outf, outg,
            w1mask + (size_t)l * WID * DIMS,
            w1mask + (size_t)PF_W1 + (size_t)l * WID * DIMS,
            f_b1 + (size_t)l * WID, g_b1 + (size_t)l * WID,
            womask + (size_t)l * NCOL * WID,
            womask + (size_t)PF_WOUT + (size_t)l * NCOL * WID,
            f_bout + (size_t)l * NCOL, g_bout + (size_t)l * NCOL,
            ldf, ldg);
    }
}